// Round 9
// baseline (171.320 us; speedup 1.0000x reference)
//
#include <hip/hip_runtime.h>
#include <hip/hip_bf16.h>

#define B_  8
#define C_  384
#define N_  1024
#define NH_ 12
#define HD_ 32

typedef __bf16 bf16x8 __attribute__((ext_vector_type(8)));
typedef __bf16 bf16x2 __attribute__((ext_vector_type(2)));
typedef float  f32x4  __attribute__((ext_vector_type(4)));

typedef const __attribute__((address_space(1))) unsigned int guint;
typedef __attribute__((address_space(3))) unsigned int luint;

__device__ __forceinline__ ushort f2b(float f) {
    unsigned int i = __float_as_uint(f);
    unsigned int r = i + 0x7fffu + ((i >> 16) & 1u);  // RNE
    return (ushort)(r >> 16);
}
// packed fp32x2 -> bf16x2 (RNE)
__device__ __forceinline__ unsigned pk2(float a, float b) {
#if __has_builtin(__builtin_amdgcn_cvt_pk_bf16_f32)
    bf16x2 t = __builtin_amdgcn_cvt_pk_bf16_f32(a, b);
    return __builtin_bit_cast(unsigned, t);
#else
    return (unsigned)f2b(a) | ((unsigned)f2b(b) << 16);
#endif
}

#if __has_builtin(__builtin_amdgcn_exp2f)
#define EXP2 __builtin_amdgcn_exp2f
#else
#define EXP2 exp2f
#endif

__device__ __forceinline__ void gl2lds16(const void* g, void* l) {
    __builtin_amdgcn_global_load_lds((guint*)g, (luint*)l, 16, 0, 0);
}

#define C1_ 0.25505654204433796f   // scale * log2e
#define C2_ 1.4426950408889634f    // log2e
#define TS_ 3972                   // padded per-head table stride (16B-aligned)

// ---------------------------------------------------------------------------
// setup (verified): x-transpose + weight conversion + bias-table prep.
// ---------------------------------------------------------------------------
__global__ __launch_bounds__(256) void setup(
    const float* __restrict__ x, const float* __restrict__ q_w,
    const float* __restrict__ kv_w, const float* __restrict__ proj_w,
    const float* __restrict__ q_b, const float* __restrict__ kv_b,
    const float* __restrict__ tab,
    ushort* __restrict__ xT, float* __restrict__ tabT,
    ushort* __restrict__ Wall, ushort* __restrict__ PW,
    float* __restrict__ ballf)
{
    __shared__ ushort T[64 * 72];
    const int bx = blockIdx.x, tid = threadIdx.x;

    if (bx < 768) {
        int t = bx;
        int nx = t & 15, cy = (t >> 4) % 6, b = t / 96;
        int n0 = nx * 64, c0 = cy * 64;
        {
            int i = tid >> 2;            // c-local
            int ns = (tid & 3) * 16;     // n-local
            const float* src = x + ((size_t)b * C_ + c0 + i) * N_ + n0 + ns;
            #pragma unroll
            for (int k4 = 0; k4 < 4; ++k4) {
                float4 f = *(const float4*)(src + k4 * 4);
                T[(ns + k4 * 4 + 0) * 72 + i] = f2b(f.x);
                T[(ns + k4 * 4 + 1) * 72 + i] = f2b(f.y);
                T[(ns + k4 * 4 + 2) * 72 + i] = f2b(f.z);
                T[(ns + k4 * 4 + 3) * 72 + i] = f2b(f.w);
            }
        }
        __syncthreads();
        {
            int j = tid >> 2;            // n-local
            int cs = (tid & 3) * 16;     // c-local
            ushort* dst = xT + ((size_t)b * N_ + n0 + j) * C_ + c0 + cs;
            *(uint4*)dst       = *(const uint4*)&T[j * 72 + cs];
            *(uint4*)(dst + 8) = *(const uint4*)&T[j * 72 + cs + 8];
        }
    } else if (bx < 1346) {
        const int NW4 = 110592, NP4 = 36864, NB4 = 288;
        int t = (bx - 768) * 256 + tid;
        if (t < NW4) {
            int e = t * 4;
            float4 f = (e < 147456) ? *(const float4*)(q_w + e)
                                    : *(const float4*)(kv_w + e - 147456);
            uint2 u;
            u.x = pk2(f.x, f.y); u.y = pk2(f.z, f.w);
            *(uint2*)(Wall + e) = u;
        } else if (t < NW4 + NP4) {
            int e = (t - NW4) * 4;
            float4 f = *(const float4*)(proj_w + e);
            uint2 u;
            u.x = pk2(f.x, f.y); u.y = pk2(f.z, f.w);
            *(uint2*)(PW + e) = u;
        } else if (t < NW4 + NP4 + NB4) {
            int e = (t - NW4 - NP4) * 4;
            float4 f = (e < 384) ? *(const float4*)(q_b + e)
                                 : *(const float4*)(kv_b + e - 384);
            *(float4*)(ballf + e) = f;
        }
    } else {
        int h = bx - 1346;
        for (int i = tid; i < 3969; i += 256)
            tabT[h * TS_ + i] = tab[(size_t)(3968 - i) * NH_ + h] * C2_;
        if (tid < 3) tabT[h * TS_ + 3969 + tid] = 0.0f;
    }
}

// ---------------------------------------------------------------------------
// qkv_gemm7 (round-6 verified best): 128n x 64d tiles, 1152 blocks, dbuf.
// ---------------------------------------------------------------------------
__global__ __launch_bounds__(256) void qkv_gemm7(
    const ushort* __restrict__ xT, const ushort* __restrict__ Wall,
    const float* __restrict__ ballf, ushort* __restrict__ Qt,
    ushort* __restrict__ Kt, ushort* __restrict__ Vtc)
{
    const int b = blockIdx.z, n0 = blockIdx.x * 128, d0 = blockIdx.y * 64;
    __shared__ ushort As[2][128 * 32];   // 16 KB
    __shared__ ushort Bs[2][64 * 32];    //  8 KB
    const int tid = threadIdx.x;
    const int lane = tid & 63, wave = tid >> 6;
    const int quad = lane >> 4, l16 = lane & 15;
    const int wn = (wave & 1) * 64, wd = (wave >> 1) * 32;

    f32x4 acc[4][2] = {};                // [n][d]
    const ushort* xb = xT + ((size_t)b * N_ + n0) * C_;
    const ushort* wb2 = Wall + (size_t)d0 * C_;
    const int rowA = wave * 16 + (lane >> 2);
    const int fstage = ((lane >> 2) ^ (lane >> 4)) & 3;           // staging swizzle
    const int coff = ((lane & 3) ^ fstage) * 8;
    const int fread = ((l16 & 3) ^ ((l16 >> 2) & 3));             // read swizzle
    const bool isV = (d0 >= 768);
    const int lo = wave * 512;           // ushort offset of this wave's 1KB chunk

    // prologue: stage K-step 0 into buf 0
    #pragma unroll
    for (int k = 0; k < 2; ++k)
        gl2lds16(xb + (size_t)(k * 64 + rowA) * C_ + coff, &As[0][k * 2048 + lo]);
    gl2lds16(wb2 + (size_t)rowA * C_ + coff, &Bs[0][lo]);
    __syncthreads();

    int cur = 0;
    for (int it = 0; it < 12; ++it) {
        if (it < 11) {
            int c0 = (it + 1) * 32;
            #pragma unroll
            for (int k = 0; k < 2; ++k)
                gl2lds16(xb + (size_t)(k * 64 + rowA) * C_ + c0 + coff,
                         &As[cur ^ 1][k * 2048 + lo]);
            gl2lds16(wb2 + (size_t)rowA * C_ + c0 + coff, &Bs[cur ^ 1][lo]);
        }
        bf16x8 af[4], bfr[2];
        #pragma unroll
        for (int i = 0; i < 4; ++i)
            af[i] = *(const bf16x8*)&As[cur][(wn + i * 16 + l16) * 32 + (quad ^ fread) * 8];
        #pragma unroll
        for (int j = 0; j < 2; ++j)
            bfr[j] = *(const bf16x8*)&Bs[cur][(wd + j * 16 + l16) * 32 + (quad ^ fread) * 8];
        if (!isV) {
            #pragma unroll
            for (int i = 0; i < 2; ++i)
                #pragma unroll
                for (int j = 0; j < 4; ++j)
                    acc[j][i] = __builtin_amdgcn_mfma_f32_16x16x32_bf16(bfr[i], af[j], acc[j][i], 0, 0, 0);
        } else {
            #pragma unroll
            for (int i = 0; i < 4; ++i)
                #pragma unroll
                for (int j = 0; j < 2; ++j)
                    acc[i][j] = __builtin_amdgcn_mfma_f32_16x16x32_bf16(af[i], bfr[j], acc[i][j], 0, 0, 0);
        }
        __syncthreads();
        cur ^= 1;
    }

    if (!isV) {
        ushort* dst = (d0 < 384) ? Qt : Kt;
        const float sc = (d0 < 384) ? C1_ : 1.0f;
        const int reg0 = (d0 < 384) ? 0 : 384;
        #pragma unroll
        for (int i = 0; i < 2; ++i) {
            int dloc = wd + i * 16;
            int dg = d0 - reg0 + dloc;
            int h = dg >> 5;
            int dc = (dg & 31) + quad * 4;
            float4 bvv = *(const float4*)(ballf + d0 + dloc + quad * 4);
            size_t hb = (size_t)(b * NH_ + h) * N_;
            #pragma unroll
            for (int j = 0; j < 4; ++j) {
                int n = n0 + wn + j * 16 + l16;
                uint2 w;
                w.x = pk2((acc[j][i][0] + bvv.x) * sc, (acc[j][i][1] + bvv.y) * sc);
                w.y = pk2((acc[j][i][2] + bvv.z) * sc, (acc[j][i][3] + bvv.w) * sc);
                *(uint2*)(dst + (hb + n) * 32 + dc) = w;
            }
        }
    } else {
        #pragma unroll
        for (int j = 0; j < 2; ++j) {
            int dloc = wd + j * 16 + l16;
            int vd = d0 - 768 + dloc;
            int h = vd >> 5, dc = vd & 31;
            float bv = ballf[d0 + dloc];
            size_t hbase = (size_t)(b * NH_ + h) * 32768 + dc * 32;
            #pragma unroll
            for (int i = 0; i < 4; ++i) {
                int n = n0 + wn + i * 16 + quad * 4;
                size_t cbase = hbase + (size_t)((n >> 5)) * 1024 + (n & 31);
                uint2 w;
                w.x = pk2(acc[i][j][0] + bv, acc[i][j][1] + bv);
                w.y = pk2(acc[i][j][2] + bv, acc[i][j][3] + bv);
                *(uint2*)(Vtc + cbase) = w;
            }
        }
    }
}

// ---------------------------------------------------------------------------
// attn13: TLP experiment, P-layout bug fixed. 1 strip per wave (attn10's
// st=0 path with IDENTICAL P addressing: 1024 ushorts/wave, l16*64 rows,
// chunk*4 scaling). Grid 1536 blocks, LDS ~24KB, __launch_bounds__(256,4)
// -> 4 blocks/CU resident (was 3).
// ---------------------------------------------------------------------------
__global__ __launch_bounds__(256, 4) void attn13(
    const ushort* __restrict__ Qt, const ushort* __restrict__ Kt,
    const ushort* __restrict__ Vtc, const float* __restrict__ tabT,
    ushort* __restrict__ O)
{
    const int bid = blockIdx.x;      // (b*12+h) + 96*nx, nx in [0,16)
    const int bh96 = bid % 96;
    const int nx = bid / 96;
    const int b = bh96 / 12, h = bh96 % 12;

    __shared__ float tabL[TS_];      // 15888 B
    __shared__ ushort Pa[4096];      // 4 waves x 16 x 64 ushorts = 8192 B

    const int tid = threadIdx.x;
    const int lane = tid & 63, wave = tid >> 6;
    const int quad = lane >> 4, l16 = lane & 15;
    const int bh = b * NH_ + h;

    {
        const float* th = tabT + h * TS_;
        int i = tid * 4;
        #pragma unroll
        for (int k = 0; k < 4; ++k) {
            if (i < TS_) *(float4*)&tabL[i] = *(const float4*)&th[i];
            i += 1024;
        }
    }
    __syncthreads();

    const int qs0 = nx * 4 + wave;   // strip index in [0,64)
    const ushort* Kbh = Kt + (size_t)bh * N_ * 32;
    const ushort* Vbh = Vtc + (size_t)bh * 16 * 2048;

    // Q B-frag (col=q=l16, k=dc=quad*8+j)
    bf16x8 qf;
    {
        int q = qs0 * 16 + l16;
        qf = *(const bf16x8*)(Qt + ((size_t)bh * N_ + q) * 32 + quad * 8);
    }
    int ibx0;
    {
        int q = qs0 * 16 + l16;
        ibx0 = (31 - (q >> 5)) * 63 + (31 - (q & 31));
    }

    bf16x8 ones;
    #pragma unroll
    for (int j = 0; j < 8; ++j) ones[j] = (__bf16)1.0f;

    f32x4 oacc[2] = {};
    f32x4 lacc = {};

    ushort* Pw = &Pa[wave * 1024];   // 16 rows x 64 ushorts (attn10 layout)
    const int pswz = l16 & 0xE;

    for (int mc = 0; mc < 16; ++mc) {
        // K A-frags: A[m=l16][k=quad*8+j] per 16-row tile (1KB line-contained)
        const ushort* kp = Kbh + mc * 64 * 32;
        bf16x8 k0 = *(const bf16x8*)(kp + (0 * 16 + l16) * 32 + quad * 8);
        bf16x8 k1 = *(const bf16x8*)(kp + (1 * 16 + l16) * 32 + quad * 8);
        bf16x8 k2 = *(const bf16x8*)(kp + (2 * 16 + l16) * 32 + quad * 8);
        bf16x8 k3 = *(const bf16x8*)(kp + (3 * 16 + l16) * 32 + quad * 8);
        // V^T A-frags: A[dc=dt*16+l16][m=kc*32+quad*8+j] (1KB line-contained)
        const ushort* vp = Vbh + mc * 2048;
        bf16x8 va[2][2];
        #pragma unroll
        for (int kc = 0; kc < 2; ++kc)
            #pragma unroll
            for (int dt = 0; dt < 2; ++dt)
                va[kc][dt] = *(const bf16x8*)(vp + kc * 1024 + (dt * 16 + l16) * 32 + quad * 8);

        // 4 shared bias gathers (st=0 set of attn10)
        const float* Tb = tabL + ibx0 + mc * 126 + quad * 4;
        f32x4 tv0, tv16, tv63, tv79;
        #pragma unroll
        for (int e = 0; e < 4; ++e) {
            tv0[e]  = Tb[e];
            tv16[e] = Tb[e + 16];
            tv63[e] = Tb[e + 63];
            tv79[e] = Tb[e + 79];
        }

        __builtin_amdgcn_s_setprio(1);
        f32x4 s0 = __builtin_amdgcn_mfma_f32_16x16x32_bf16(k0, qf, tv0,  0, 0, 0);
        f32x4 s1 = __builtin_amdgcn_mfma_f32_16x16x32_bf16(k1, qf, tv16, 0, 0, 0);
        f32x4 s2 = __builtin_amdgcn_mfma_f32_16x16x32_bf16(k2, qf, tv63, 0, 0, 0);
        f32x4 s3 = __builtin_amdgcn_mfma_f32_16x16x32_bf16(k3, qf, tv79, 0, 0, 0);
        __builtin_amdgcn_s_setprio(0);

        f32x4 sv[4] = {s0, s1, s2, s3};
        #pragma unroll
        for (int t = 0; t < 4; ++t) {
            float p0 = EXP2(sv[t][0]);
            float p1 = EXP2(sv[t][1]);
            float p2 = EXP2(sv[t][2]);
            float p3 = EXP2(sv[t][3]);
            uint2 w;
            w.x = pk2(p0, p1);
            w.y = pk2(p2, p3);
            *(uint2*)(Pw + l16 * 64 + (((t * 4 + quad) ^ pswz) * 4)) = w;
        }
        // PV + rowsum on the matrix pipe
        __builtin_amdgcn_s_setprio(1);
        #pragma unroll
        for (int kc = 0; kc < 2; ++kc) {
            bf16x8 pb = *(const bf16x8*)(Pw + l16 * 64 + (((kc * 8 + quad * 2) ^ pswz) * 4));
            lacc    = __builtin_amdgcn_mfma_f32_16x16x32_bf16(ones, pb, lacc, 0, 0, 0);
            oacc[0] = __builtin_amdgcn_mfma_f32_16x16x32_bf16(va[kc][0], pb, oacc[0], 0, 0, 0);
            oacc[1] = __builtin_amdgcn_mfma_f32_16x16x32_bf16(va[kc][1], pb, oacc[1], 0, 0, 0);
        }
        __builtin_amdgcn_s_setprio(0);
    }

    // epilogue: O[b][q][h*32+dc]
    {
        float inv = 1.0f / lacc[0];
        int q = qs0 * 16 + l16;
        ushort* ob = O + ((size_t)(b * N_ + q)) * C_ + h * HD_;
        #pragma unroll
        for (int dt = 0; dt < 2; ++dt) {
            uint2 w;
            w.x = pk2(oacc[dt][0] * inv, oacc[dt][1] * inv);
            w.y = pk2(oacc[dt][2] * inv, oacc[dt][3] * inv);
            *(uint2*)(ob + dt * 16 + quad * 4) = w;
        }
    }
}

// ---------------------------------------------------------------------------
// proj64 (round-6 verified): 64x64 tiles, 768 blocks = 3/CU, dbuf staging.
// ---------------------------------------------------------------------------
__global__ __launch_bounds__(256) void proj64(
    const ushort* __restrict__ O, const ushort* __restrict__ PW,
    const float* __restrict__ pb, float* __restrict__ out)
{
    __shared__ ushort As_[2][2048];   // 8 KB
    __shared__ ushort Bs_[2][2048];   // 8 KB
    const int tid = threadIdx.x;
    const int lane = tid & 63, wave = tid >> 6;
    const int quad = lane >> 4, l16 = lane & 15;
    const int nx = blockIdx.x, dy = blockIdx.y, b = blockIdx.z;
    const int n0 = nx * 64, d0 = dy * 64;
    const int wd = (wave & 1) * 32, wn = (wave >> 1) * 32;

    f32x4 acc[2][2] = {};
    const ushort* ab = PW + (size_t)d0 * C_;
    const ushort* bbp = O + ((size_t)b * N_ + n0) * C_;
    const int rowA = wave * 16 + (lane >> 2);
    const int fstage = ((lane >> 2) ^ (lane >> 4)) & 3;
    const int coff = ((lane & 3) ^ fstage) * 8;
    const int fread = ((l16 & 3) ^ ((l16 >> 2) & 3));
    const int lo = wave * 512;

    gl2lds16(ab + (size_t)rowA * C_ + coff, &As_[0][lo]);
    gl2lds16(bbp + (size_t)rowA * C_ + coff, &Bs_[0][lo]);
    __syncthreads();

    int cur = 0;
    for (int it = 0; it < 12; ++it) {
        if (it < 11) {
            int c0 = (it + 1) * 32;
            gl2lds16(ab + (size_t)rowA * C_ + c0 + coff, &As_[cur ^ 1][lo]);
            gl2lds16(bbp + (size_t)rowA * C_ + c0 + coff, &Bs_[cur ^ 1][lo]);
        }
        bf16x8 af[2], bfr[2];
        #pragma unroll
        for (int i = 0; i < 2; ++i)
            af[i] = *(const bf16x8*)&As_[cur][(wd + i * 16 + l16) * 32 + (quad ^ fread) * 8];
        #pragma unroll
        for (int j = 0; j < 2; ++j)
            bfr[j] = *(const bf16x8*)&Bs_[cur][(wn + j * 16 + l16) * 32 + (quad ^ fread) * 8];
        #pragma unroll
        for (int i = 0; i < 2; ++i)
            #pragma unroll
            for (int j = 0; j < 2; ++j)
                acc[i][j] = __builtin_amdgcn_mfma_f32_16x16x32_bf16(af[i], bfr[j], acc[i][j], 0, 0, 0);
        __syncthreads();
        cur ^= 1;
    }

    #pragma unroll
    for (int i = 0; i < 2; ++i) {
        #pragma unroll
        for (int r = 0; r < 4; ++r) {
            int d = d0 + wd + i * 16 + quad * 4 + r;
            float bv = pb[d];
            float* op = out + ((size_t)b * C_ + d) * N_ + n0 + wn;
            #pragma unroll
            for (int j = 0; j < 2; ++j)
                op[j * 16 + l16] = acc[i][j][r] + bv;
        }
    }
}

// ---------------------------------------------------------------------------
extern "C" void kernel_launch(void* const* d_in, const int* in_sizes, int n_in,
                              void* d_out, int out_size, void* d_ws, size_t ws_size,
                              hipStream_t stream)
{
    const float* x      = (const float*)d_in[0];
    const float* q_w    = (const float*)d_in[1];
    const float* q_b    = (const float*)d_in[2];
    const float* kv_w   = (const float*)d_in[3];
    const float* kv_b   = (const float*)d_in[4];
    const float* proj_w = (const float*)d_in[5];
    const float* proj_b = (const float*)d_in[6];
    const float* rpb    = (const float*)d_in[7];
    float* out = (float*)d_out;

    char* ws = (char*)d_ws;
    ushort* xT    = (ushort*)(ws);                       //  6,291,456
    ushort* Qt    = (ushort*)(ws +  6291456);            //  6,291,456
    ushort* Kt    = (ushort*)(ws + 12582912);            //  6,291,456
    ushort* Vtc   = (ushort*)(ws + 18874368);            //  6,291,456
    ushort* O     = (ushort*)(ws + 25165824);            //  6,291,456
    float*  tabT  = (float*) (ws + 31457280);            //    190,656 (12 x 3972 x 4)
    ushort* Wall  = (ushort*)(ws + 31647936);            //    884,736
    ushort* PW    = (ushort*)(ws + 32532672);            //    294,912
    float*  ballf = (float*) (ws + 32827584);            //      4,608

    setup     <<<dim3(1358), 256, 0, stream>>>(x, q_w, kv_w, proj_w, q_b, kv_b, rpb,
                                               xT, tabT, Wall, PW, ballf);
    qkv_gemm7 <<<dim3(8, 18, B_), 256, 0, stream>>>(xT, Wall, ballf, Qt, Kt, Vtc);
    attn13    <<<dim3(1536), 256, 0, stream>>>(Qt, Kt, Vtc, tabT, O);
    proj64    <<<dim3(16, 6, B_), 256, 0, stream>>>(O, PW, proj_b, out);
}

// Round 10
// 144.575 us; speedup vs baseline: 1.1850x; 1.1850x over previous
//
#include <hip/hip_runtime.h>
#include <hip/hip_bf16.h>

#define B_  8
#define C_  384
#define N_  1024
#define NH_ 12
#define HD_ 32

typedef __bf16 bf16x8 __attribute__((ext_vector_type(8)));
typedef __bf16 bf16x2 __attribute__((ext_vector_type(2)));
typedef float  f32x4  __attribute__((ext_vector_type(4)));

typedef const __attribute__((address_space(1))) unsigned int guint;
typedef __attribute__((address_space(3))) unsigned int luint;

__device__ __forceinline__ ushort f2b(float f) {
    unsigned int i = __float_as_uint(f);
    unsigned int r = i + 0x7fffu + ((i >> 16) & 1u);  // RNE
    return (ushort)(r >> 16);
}
// packed fp32x2 -> bf16x2 (RNE)
__device__ __forceinline__ unsigned pk2(float a, float b) {
#if __has_builtin(__builtin_amdgcn_cvt_pk_bf16_f32)
    bf16x2 t = __builtin_amdgcn_cvt_pk_bf16_f32(a, b);
    return __builtin_bit_cast(unsigned, t);
#else
    return (unsigned)f2b(a) | ((unsigned)f2b(b) << 16);
#endif
}

#if __has_builtin(__builtin_amdgcn_exp2f)
#define EXP2 __builtin_amdgcn_exp2f
#else
#define EXP2 exp2f
#endif

__device__ __forceinline__ void gl2lds16(const void* g, void* l) {
    __builtin_amdgcn_global_load_lds((guint*)g, (luint*)l, 16, 0, 0);
}

#define C1_ 0.25505654204433796f   // scale * log2e
#define C2_ 1.4426950408889634f    // log2e
#define TS_ 3972                   // padded per-head table stride (16B-aligned)

// ---------------------------------------------------------------------------
// setup (verified): x-transpose + weight conversion + bias-table prep.
// ---------------------------------------------------------------------------
__global__ __launch_bounds__(256) void setup(
    const float* __restrict__ x, const float* __restrict__ q_w,
    const float* __restrict__ kv_w, const float* __restrict__ proj_w,
    const float* __restrict__ q_b, const float* __restrict__ kv_b,
    const float* __restrict__ tab,
    ushort* __restrict__ xT, float* __restrict__ tabT,
    ushort* __restrict__ Wall, ushort* __restrict__ PW,
    float* __restrict__ ballf)
{
    __shared__ ushort T[64 * 72];
    const int bx = blockIdx.x, tid = threadIdx.x;

    if (bx < 768) {
        int t = bx;
        int nx = t & 15, cy = (t >> 4) % 6, b = t / 96;
        int n0 = nx * 64, c0 = cy * 64;
        {
            int i = tid >> 2;            // c-local
            int ns = (tid & 3) * 16;     // n-local
            const float* src = x + ((size_t)b * C_ + c0 + i) * N_ + n0 + ns;
            #pragma unroll
            for (int k4 = 0; k4 < 4; ++k4) {
                float4 f = *(const float4*)(src + k4 * 4);
                T[(ns + k4 * 4 + 0) * 72 + i] = f2b(f.x);
                T[(ns + k4 * 4 + 1) * 72 + i] = f2b(f.y);
                T[(ns + k4 * 4 + 2) * 72 + i] = f2b(f.z);
                T[(ns + k4 * 4 + 3) * 72 + i] = f2b(f.w);
            }
        }
        __syncthreads();
        {
            int j = tid >> 2;            // n-local
            int cs = (tid & 3) * 16;     // c-local
            ushort* dst = xT + ((size_t)b * N_ + n0 + j) * C_ + c0 + cs;
            *(uint4*)dst       = *(const uint4*)&T[j * 72 + cs];
            *(uint4*)(dst + 8) = *(const uint4*)&T[j * 72 + cs + 8];
        }
    } else if (bx < 1346) {
        const int NW4 = 110592, NP4 = 36864, NB4 = 288;
        int t = (bx - 768) * 256 + tid;
        if (t < NW4) {
            int e = t * 4;
            float4 f = (e < 147456) ? *(const float4*)(q_w + e)
                                    : *(const float4*)(kv_w + e - 147456);
            uint2 u;
            u.x = pk2(f.x, f.y); u.y = pk2(f.z, f.w);
            *(uint2*)(Wall + e) = u;
        } else if (t < NW4 + NP4) {
            int e = (t - NW4) * 4;
            float4 f = *(const float4*)(proj_w + e);
            uint2 u;
            u.x = pk2(f.x, f.y); u.y = pk2(f.z, f.w);
            *(uint2*)(PW + e) = u;
        } else if (t < NW4 + NP4 + NB4) {
            int e = (t - NW4 - NP4) * 4;
            float4 f = (e < 384) ? *(const float4*)(q_b + e)
                                 : *(const float4*)(kv_b + e - 384);
            *(float4*)(ballf + e) = f;
        }
    } else {
        int h = bx - 1346;
        for (int i = tid; i < 3969; i += 256)
            tabT[h * TS_ + i] = tab[(size_t)(3968 - i) * NH_ + h] * C2_;
        if (tid < 3) tabT[h * TS_ + 3969 + tid] = 0.0f;
    }
}

// ---------------------------------------------------------------------------
// qkv_gemm9: qkv_gemm7 body + TRUE async pipeline (T4): counted
// s_waitcnt vmcnt(3) + raw s_barrier. __syncthreads' vmcnt(0) drain was
// serializing the prefetch (r5/r6 dbuf null explained). The next tile's 3
// gl2lds16 stay in flight across the barrier; only the current tile's
// loads are waited on. Last iter drains with vmcnt(0).
// ---------------------------------------------------------------------------
__global__ __launch_bounds__(256) void qkv_gemm9(
    const ushort* __restrict__ xT, const ushort* __restrict__ Wall,
    const float* __restrict__ ballf, ushort* __restrict__ Qt,
    ushort* __restrict__ Kt, ushort* __restrict__ Vtc)
{
    const int b = blockIdx.z, n0 = blockIdx.x * 128, d0 = blockIdx.y * 64;
    __shared__ ushort As[2][128 * 32];   // 16 KB
    __shared__ ushort Bs[2][64 * 32];    //  8 KB
    const int tid = threadIdx.x;
    const int lane = tid & 63, wave = tid >> 6;
    const int quad = lane >> 4, l16 = lane & 15;
    const int wn = (wave & 1) * 64, wd = (wave >> 1) * 32;

    f32x4 acc[4][2] = {};                // [n][d]
    const ushort* xb = xT + ((size_t)b * N_ + n0) * C_;
    const ushort* wb2 = Wall + (size_t)d0 * C_;
    const int rowA = wave * 16 + (lane >> 2);
    const int fstage = ((lane >> 2) ^ (lane >> 4)) & 3;           // staging swizzle
    const int coff = ((lane & 3) ^ fstage) * 8;
    const int fread = ((l16 & 3) ^ ((l16 >> 2) & 3));             // read swizzle
    const bool isV = (d0 >= 768);
    const int lo = wave * 512;           // ushort offset of this wave's 1KB chunk

    // prologue: stage K-step 0 into buf 0 (3 vmem ops/wave outstanding)
    #pragma unroll
    for (int k = 0; k < 2; ++k)
        gl2lds16(xb + (size_t)(k * 64 + rowA) * C_ + coff, &As[0][k * 2048 + lo]);
    gl2lds16(wb2 + (size_t)rowA * C_ + coff, &Bs[0][lo]);

    int cur = 0;
    for (int it = 0; it < 12; ++it) {
        if (it < 11) {
            int c0 = (it + 1) * 32;
            #pragma unroll
            for (int k = 0; k < 2; ++k)
                gl2lds16(xb + (size_t)(k * 64 + rowA) * C_ + c0 + coff,
                         &As[cur ^ 1][k * 2048 + lo]);
            gl2lds16(wb2 + (size_t)rowA * C_ + c0 + coff, &Bs[cur ^ 1][lo]);
            asm volatile("s_waitcnt vmcnt(3)" ::: "memory");   // tile t landed; t+1 in flight
        } else {
            asm volatile("s_waitcnt vmcnt(0)" ::: "memory");   // final tile drain
        }
        __builtin_amdgcn_sched_barrier(0);
        __builtin_amdgcn_s_barrier();        // all waves' tile-t loads landed

        bf16x8 af[4], bfr[2];
        #pragma unroll
        for (int i = 0; i < 4; ++i)
            af[i] = *(const bf16x8*)&As[cur][(wn + i * 16 + l16) * 32 + (quad ^ fread) * 8];
        #pragma unroll
        for (int j = 0; j < 2; ++j)
            bfr[j] = *(const bf16x8*)&Bs[cur][(wd + j * 16 + l16) * 32 + (quad ^ fread) * 8];
        if (!isV) {
            #pragma unroll
            for (int i = 0; i < 2; ++i)
                #pragma unroll
                for (int j = 0; j < 4; ++j)
                    acc[j][i] = __builtin_amdgcn_mfma_f32_16x16x32_bf16(bfr[i], af[j], acc[j][i], 0, 0, 0);
        } else {
            #pragma unroll
            for (int i = 0; i < 4; ++i)
                #pragma unroll
                for (int j = 0; j < 2; ++j)
                    acc[i][j] = __builtin_amdgcn_mfma_f32_16x16x32_bf16(af[i], bfr[j], acc[i][j], 0, 0, 0);
        }
        __builtin_amdgcn_s_barrier();        // reads of buf[cur] done before t+2 overwrites it
        cur ^= 1;
    }

    if (!isV) {
        ushort* dst = (d0 < 384) ? Qt : Kt;
        const float sc = (d0 < 384) ? C1_ : 1.0f;
        const int reg0 = (d0 < 384) ? 0 : 384;
        #pragma unroll
        for (int i = 0; i < 2; ++i) {
            int dloc = wd + i * 16;
            int dg = d0 - reg0 + dloc;
            int h = dg >> 5;
            int dc = (dg & 31) + quad * 4;
            float4 bvv = *(const float4*)(ballf + d0 + dloc + quad * 4);
            size_t hb = (size_t)(b * NH_ + h) * N_;
            #pragma unroll
            for (int j = 0; j < 4; ++j) {
                int n = n0 + wn + j * 16 + l16;
                uint2 w;
                w.x = pk2((acc[j][i][0] + bvv.x) * sc, (acc[j][i][1] + bvv.y) * sc);
                w.y = pk2((acc[j][i][2] + bvv.z) * sc, (acc[j][i][3] + bvv.w) * sc);
                *(uint2*)(dst + (hb + n) * 32 + dc) = w;
            }
        }
    } else {
        #pragma unroll
        for (int j = 0; j < 2; ++j) {
            int dloc = wd + j * 16 + l16;
            int vd = d0 - 768 + dloc;
            int h = vd >> 5, dc = vd & 31;
            float bv = ballf[d0 + dloc];
            size_t hbase = (size_t)(b * NH_ + h) * 32768 + dc * 32;
            #pragma unroll
            for (int i = 0; i < 4; ++i) {
                int n = n0 + wn + i * 16 + quad * 4;
                size_t cbase = hbase + (size_t)((n >> 5)) * 1024 + (n & 31);
                uint2 w;
                w.x = pk2(acc[i][j][0] + bv, acc[i][j][1] + bv);
                w.y = pk2(acc[i][j][2] + bv, acc[i][j][3] + bv);
                *(uint2*)(Vtc + cbase) = w;
            }
        }
    }
}

// ---------------------------------------------------------------------------
// attn11 (round-6 verified best): reg-dbuf K/V prefetch + strip-split.
// ---------------------------------------------------------------------------
#define LOADKV(K0,K1,K2,K3,V00,V01,V10,V11, MC)                                 \
    { const ushort* kp_ = Kbh + (MC) * 2048;                                    \
      K0 = *(const bf16x8*)(kp_ + ( 0 + l16) * 32 + quad * 8);                  \
      K1 = *(const bf16x8*)(kp_ + (16 + l16) * 32 + quad * 8);                  \
      K2 = *(const bf16x8*)(kp_ + (32 + l16) * 32 + quad * 8);                  \
      K3 = *(const bf16x8*)(kp_ + (48 + l16) * 32 + quad * 8);                  \
      const ushort* vp_ = Vbh + (MC) * 2048;                                    \
      V00 = *(const bf16x8*)(vp_ +        ( 0 + l16) * 32 + quad * 8);          \
      V01 = *(const bf16x8*)(vp_ +        (16 + l16) * 32 + quad * 8);          \
      V10 = *(const bf16x8*)(vp_ + 1024 + ( 0 + l16) * 32 + quad * 8);          \
      V11 = *(const bf16x8*)(vp_ + 1024 + (16 + l16) * 32 + quad * 8); }

#define COMPUTE(MC, K0,K1,K2,K3,V00,V01,V10,V11)                                \
    { const float* Tb = tabL + ibx0 + (MC) * 126 + quad * 4;                    \
      f32x4 tvm16, tv0, tv16, tv47, tv63, tv79;                                 \
      _Pragma("unroll")                                                         \
      for (int e = 0; e < 4; ++e) {                                             \
          tvm16[e] = Tb[e - 16];                                                \
          tv0[e]   = Tb[e];                                                     \
          tv16[e]  = Tb[e + 16];                                                \
          tv47[e]  = Tb[e + 47];                                                \
          tv63[e]  = Tb[e + 63];                                                \
          tv79[e]  = Tb[e + 79];                                                \
      }                                                                         \
      f32x4 cbs[2][4] = {{tv0, tv16, tv63, tv79}, {tvm16, tv0, tv47, tv63}};    \
      _Pragma("unroll")                                                         \
      for (int st = 0; st < 2; ++st) {                                          \
          __builtin_amdgcn_s_setprio(1);                                        \
          f32x4 s0 = __builtin_amdgcn_mfma_f32_16x16x32_bf16(K0, qf[st], cbs[st][0], 0, 0, 0); \
          f32x4 s1 = __builtin_amdgcn_mfma_f32_16x16x32_bf16(K1, qf[st], cbs[st][1], 0, 0, 0); \
          f32x4 s2 = __builtin_amdgcn_mfma_f32_16x16x32_bf16(K2, qf[st], cbs[st][2], 0, 0, 0); \
          f32x4 s3 = __builtin_amdgcn_mfma_f32_16x16x32_bf16(K3, qf[st], cbs[st][3], 0, 0, 0); \
          __builtin_amdgcn_s_setprio(0);                                        \
          ushort* Pw = PwBase + st * 1024;                                      \
          f32x4 sv[4] = {s0, s1, s2, s3};                                       \
          _Pragma("unroll")                                                     \
          for (int t = 0; t < 4; ++t) {                                         \
              float p0 = EXP2(sv[t][0]);                                        \
              float p1 = EXP2(sv[t][1]);                                        \
              float p2 = EXP2(sv[t][2]);                                        \
              float p3 = EXP2(sv[t][3]);                                        \
              uint2 w;                                                          \
              w.x = pk2(p0, p1);                                                \
              w.y = pk2(p2, p3);                                                \
              *(uint2*)(Pw + l16 * 64 + (((t * 4 + quad) ^ pswz) * 4)) = w;     \
          }                                                                     \
      }                                                                         \
      _Pragma("unroll")                                                         \
      for (int st = 0; st < 2; ++st) {                                          \
          ushort* Pw = PwBase + st * 1024;                                      \
          __builtin_amdgcn_s_setprio(1);                                        \
          { bf16x8 pb = *(const bf16x8*)(Pw + l16 * 64 + (((0 + quad * 2) ^ pswz) * 4)); \
            lacc[st]    = __builtin_amdgcn_mfma_f32_16x16x32_bf16(ones, pb, lacc[st], 0, 0, 0); \
            oacc[st][0] = __builtin_amdgcn_mfma_f32_16x16x32_bf16(V00, pb, oacc[st][0], 0, 0, 0); \
            oacc[st][1] = __builtin_amdgcn_mfma_f32_16x16x32_bf16(V01, pb, oacc[st][1], 0, 0, 0); } \
          { bf16x8 pb = *(const bf16x8*)(Pw + l16 * 64 + (((8 + quad * 2) ^ pswz) * 4)); \
            lacc[st]    = __builtin_amdgcn_mfma_f32_16x16x32_bf16(ones, pb, lacc[st], 0, 0, 0); \
            oacc[st][0] = __builtin_amdgcn_mfma_f32_16x16x32_bf16(V10, pb, oacc[st][0], 0, 0, 0); \
            oacc[st][1] = __builtin_amdgcn_mfma_f32_16x16x32_bf16(V11, pb, oacc[st][1], 0, 0, 0); } \
          __builtin_amdgcn_s_setprio(0);                                        \
      } }

__global__ __launch_bounds__(256, 3) void attn11(
    const ushort* __restrict__ Qt, const ushort* __restrict__ Kt,
    const ushort* __restrict__ Vtc, const float* __restrict__ tabT,
    ushort* __restrict__ O)
{
    const int bid = blockIdx.x;      // (b*12+h) + 96*nx
    const int bh96 = bid % 96;
    const int nx = bid / 96;
    const int b = bh96 / 12, h = bh96 % 12;

    __shared__ float tabL[TS_];
    __shared__ ushort Pa[8192];      // 4 waves x 2 strips x 16 x 64

    const int tid = threadIdx.x;
    const int lane = tid & 63, wave = tid >> 6;
    const int quad = lane >> 4, l16 = lane & 15;
    const int bh = b * NH_ + h;

    {
        const float* th = tabT + h * TS_;
        int i = tid * 4;
        #pragma unroll
        for (int k = 0; k < 4; ++k) {
            if (i < TS_) *(float4*)&tabL[i] = *(const float4*)&th[i];
            i += 1024;
        }
    }
    __syncthreads();

    const int qs0 = nx * 8 + wave * 2;
    const ushort* Kbh = Kt + (size_t)bh * N_ * 32;
    const ushort* Vbh = Vtc + (size_t)bh * 16 * 2048;

    bf16x8 qf[2];
    #pragma unroll
    for (int st = 0; st < 2; ++st) {
        int q = (qs0 + st) * 16 + l16;
        qf[st] = *(const bf16x8*)(Qt + ((size_t)bh * N_ + q) * 32 + quad * 8);
    }
    int ibx0;
    {
        int q = qs0 * 16 + l16;
        ibx0 = (31 - (q >> 5)) * 63 + (31 - (q & 31));
    }

    bf16x8 ones;
    #pragma unroll
    for (int j = 0; j < 8; ++j) ones[j] = (__bf16)1.0f;

    f32x4 oacc[2][2] = {};
    f32x4 lacc[2] = {};

    ushort* PwBase = &Pa[wave * 2048];
    const int pswz = l16 & 0xE;

    // register double-buffer: ka*/va* = current, kb*/vb* = next
    bf16x8 ka0, ka1, ka2, ka3, va00, va01, va10, va11;
    bf16x8 kb0, kb1, kb2, kb3, vb00, vb01, vb10, vb11;

    LOADKV(ka0, ka1, ka2, ka3, va00, va01, va10, va11, 0)
    for (int mc = 0; mc < 16; mc += 2) {
        LOADKV(kb0, kb1, kb2, kb3, vb00, vb01, vb10, vb11, mc + 1)
        COMPUTE(mc, ka0, ka1, ka2, ka3, va00, va01, va10, va11)
        if (mc < 14)
            LOADKV(ka0, ka1, ka2, ka3, va00, va01, va10, va11, mc + 2)
        COMPUTE(mc + 1, kb0, kb1, kb2, kb3, vb00, vb01, vb10, vb11)
    }

    #pragma unroll
    for (int st = 0; st < 2; ++st) {
        float inv = 1.0f / lacc[st][0];
        int q = (qs0 + st) * 16 + l16;
        ushort* ob = O + ((size_t)(b * N_ + q)) * C_ + h * HD_;
        #pragma unroll
        for (int dt = 0; dt < 2; ++dt) {
            uint2 w;
            w.x = pk2(oacc[st][dt][0] * inv, oacc[st][dt][1] * inv);
            w.y = pk2(oacc[st][dt][2] * inv, oacc[st][dt][3] * inv);
            *(uint2*)(ob + dt * 16 + quad * 4) = w;
        }
    }
}

// ---------------------------------------------------------------------------
// proj66: proj64 body + counted-vmcnt raw-barrier pipeline (vmcnt(2)).
// ---------------------------------------------------------------------------
__global__ __launch_bounds__(256) void proj66(
    const ushort* __restrict__ O, const ushort* __restrict__ PW,
    const float* __restrict__ pb, float* __restrict__ out)
{
    __shared__ ushort As_[2][2048];   // 8 KB
    __shared__ ushort Bs_[2][2048];   // 8 KB
    const int tid = threadIdx.x;
    const int lane = tid & 63, wave = tid >> 6;
    const int quad = lane >> 4, l16 = lane & 15;
    const int nx = blockIdx.x, dy = blockIdx.y, b = blockIdx.z;
    const int n0 = nx * 64, d0 = dy * 64;
    const int wd = (wave & 1) * 32, wn = (wave >> 1) * 32;

    f32x4 acc[2][2] = {};
    const ushort* ab = PW + (size_t)d0 * C_;
    const ushort* bbp = O + ((size_t)b * N_ + n0) * C_;
    const int rowA = wave * 16 + (lane >> 2);
    const int fstage = ((lane >> 2) ^ (lane >> 4)) & 3;
    const int coff = ((lane & 3) ^ fstage) * 8;
    const int fread = ((l16 & 3) ^ ((l16 >> 2) & 3));
    const int lo = wave * 512;

    gl2lds16(ab + (size_t)rowA * C_ + coff, &As_[0][lo]);
    gl2lds16(bbp + (size_t)rowA * C_ + coff, &Bs_[0][lo]);

    int cur = 0;
    for (int it = 0; it < 12; ++it) {
        if (it < 11) {
            int c0 = (it + 1) * 32;
            gl2lds16(ab + (size_t)rowA * C_ + c0 + coff, &As_[cur ^ 1][lo]);
            gl2lds16(bbp + (size_t)rowA * C_ + c0 + coff, &Bs_[cur ^ 1][lo]);
            asm volatile("s_waitcnt vmcnt(2)" ::: "memory");
        } else {
            asm volatile("s_waitcnt vmcnt(0)" ::: "memory");
        }
        __builtin_amdgcn_sched_barrier(0);
        __builtin_amdgcn_s_barrier();

        bf16x8 af[2], bfr[2];
        #pragma unroll
        for (int i = 0; i < 2; ++i)
            af[i] = *(const bf16x8*)&As_[cur][(wd + i * 16 + l16) * 32 + (quad ^ fread) * 8];
        #pragma unroll
        for (int j = 0; j < 2; ++j)
            bfr[j] = *(const bf16x8*)&Bs_[cur][(wn + j * 16 + l16) * 32 + (quad ^ fread) * 8];
        #pragma unroll
        for (int i = 0; i < 2; ++i)
            #pragma unroll
            for (int j = 0; j < 2; ++j)
                acc[i][j] = __builtin_amdgcn_mfma_f32_16x16x32_bf16(af[i], bfr[j], acc[i][j], 0, 0, 0);
        __builtin_amdgcn_s_barrier();
        cur ^= 1;
    }

    #pragma unroll
    for (int i = 0; i < 2; ++i) {
        #pragma unroll
        for (int r = 0; r < 4; ++r) {
            int d = d0 + wd + i * 16 + quad * 4 + r;
            float bv = pb[d];
            float* op = out + ((size_t)b * C_ + d) * N_ + n0 + wn;
            #pragma unroll
            for (int j = 0; j < 2; ++j)
                op[j * 16 + l16] = acc[i][j][r] + bv;
        }
    }
}

// ---------------------------------------------------------------------------
extern "C" void kernel_launch(void* const* d_in, const int* in_sizes, int n_in,
                              void* d_out, int out_size, void* d_ws, size_t ws_size,
                              hipStream_t stream)
{
    const float* x      = (const float*)d_in[0];
    const float* q_w    = (const float*)d_in[1];
    const float* q_b    = (const float*)d_in[2];
    const float* kv_w   = (const float*)d_in[3];
    const float* kv_b   = (const float*)d_in[4];
    const float* proj_w = (const float*)d_in[5];
    const float* proj_b = (const float*)d_in[6];
    const float* rpb    = (const float*)d_in[7];
    float* out = (float*)d_out;

    char* ws = (char*)d_ws;
    ushort* xT    = (ushort*)(ws);                       //  6,291,456
    ushort* Qt    = (ushort*)(ws +  6291456);            //  6,291,456
    ushort* Kt    = (ushort*)(ws + 12582912);            //  6,291,456
    ushort* Vtc   = (ushort*)(ws + 18874368);            //  6,291,456
    ushort* O     = (ushort*)(ws + 25165824);            //  6,291,456
    float*  tabT  = (float*) (ws + 31457280);            //    190,656 (12 x 3972 x 4)
    ushort* Wall  = (ushort*)(ws + 31647936);            //    884,736
    ushort* PW    = (ushort*)(ws + 32532672);            //    294,912
    float*  ballf = (float*) (ws + 32827584);            //      4,608

    setup     <<<dim3(1358), 256, 0, stream>>>(x, q_w, kv_w, proj_w, q_b, kv_b, rpb,
                                               xT, tabT, Wall, PW, ballf);
    qkv_gemm9 <<<dim3(8, 18, B_), 256, 0, stream>>>(xT, Wall, ballf, Qt, Kt, Vtc);
    attn11    <<<dim3(768), 256, 0, stream>>>(Qt, Kt, Vtc, tabT, O);
    proj66    <<<dim3(16, 6, B_), 256, 0, stream>>>(O, PW, proj_b, out);
}

// Round 11
// 142.509 us; speedup vs baseline: 1.2022x; 1.0145x over previous
//
#include <hip/hip_runtime.h>
#include <hip/hip_bf16.h>

#define B_  8
#define C_  384
#define N_  1024
#define NH_ 12
#define HD_ 32

typedef __bf16 bf16x8 __attribute__((ext_vector_type(8)));
typedef __bf16 bf16x2 __attribute__((ext_vector_type(2)));
typedef float  f32x4  __attribute__((ext_vector_type(4)));

typedef const __attribute__((address_space(1))) unsigned int guint;
typedef __attribute__((address_space(3))) unsigned int luint;

__device__ __forceinline__ ushort f2b(float f) {
    unsigned int i = __float_as_uint(f);
    unsigned int r = i + 0x7fffu + ((i >> 16) & 1u);  // RNE
    return (ushort)(r >> 16);
}
// packed fp32x2 -> bf16x2 (RNE)
__device__ __forceinline__ unsigned pk2(float a, float b) {
#if __has_builtin(__builtin_amdgcn_cvt_pk_bf16_f32)
    bf16x2 t = __builtin_amdgcn_cvt_pk_bf16_f32(a, b);
    return __builtin_bit_cast(unsigned, t);
#else
    return (unsigned)f2b(a) | ((unsigned)f2b(b) << 16);
#endif
}

#if __has_builtin(__builtin_amdgcn_exp2f)
#define EXP2 __builtin_amdgcn_exp2f
#else
#define EXP2 exp2f
#endif

__device__ __forceinline__ void gl2lds16(const void* g, void* l) {
    __builtin_amdgcn_global_load_lds((guint*)g, (luint*)l, 16, 0, 0);
}

#define C1_ 0.25505654204433796f   // scale * log2e
#define C2_ 1.4426950408889634f    // log2e
#define TS_ 3972                   // padded per-head table stride (16B-aligned)

// ---------------------------------------------------------------------------
// setup (verified): x-transpose + weight conversion + bias-table prep.
// ---------------------------------------------------------------------------
__global__ __launch_bounds__(256) void setup(
    const float* __restrict__ x, const float* __restrict__ q_w,
    const float* __restrict__ kv_w, const float* __restrict__ proj_w,
    const float* __restrict__ q_b, const float* __restrict__ kv_b,
    const float* __restrict__ tab,
    ushort* __restrict__ xT, float* __restrict__ tabT,
    ushort* __restrict__ Wall, ushort* __restrict__ PW,
    float* __restrict__ ballf)
{
    __shared__ ushort T[64 * 72];
    const int bx = blockIdx.x, tid = threadIdx.x;

    if (bx < 768) {
        int t = bx;
        int nx = t & 15, cy = (t >> 4) % 6, b = t / 96;
        int n0 = nx * 64, c0 = cy * 64;
        {
            int i = tid >> 2;            // c-local
            int ns = (tid & 3) * 16;     // n-local
            const float* src = x + ((size_t)b * C_ + c0 + i) * N_ + n0 + ns;
            #pragma unroll
            for (int k4 = 0; k4 < 4; ++k4) {
                float4 f = *(const float4*)(src + k4 * 4);
                T[(ns + k4 * 4 + 0) * 72 + i] = f2b(f.x);
                T[(ns + k4 * 4 + 1) * 72 + i] = f2b(f.y);
                T[(ns + k4 * 4 + 2) * 72 + i] = f2b(f.z);
                T[(ns + k4 * 4 + 3) * 72 + i] = f2b(f.w);
            }
        }
        __syncthreads();
        {
            int j = tid >> 2;            // n-local
            int cs = (tid & 3) * 16;     // c-local
            ushort* dst = xT + ((size_t)b * N_ + n0 + j) * C_ + c0 + cs;
            *(uint4*)dst       = *(const uint4*)&T[j * 72 + cs];
            *(uint4*)(dst + 8) = *(const uint4*)&T[j * 72 + cs + 8];
        }
    } else if (bx < 1346) {
        const int NW4 = 110592, NP4 = 36864, NB4 = 288;
        int t = (bx - 768) * 256 + tid;
        if (t < NW4) {
            int e = t * 4;
            float4 f = (e < 147456) ? *(const float4*)(q_w + e)
                                    : *(const float4*)(kv_w + e - 147456);
            uint2 u;
            u.x = pk2(f.x, f.y); u.y = pk2(f.z, f.w);
            *(uint2*)(Wall + e) = u;
        } else if (t < NW4 + NP4) {
            int e = (t - NW4) * 4;
            float4 f = *(const float4*)(proj_w + e);
            uint2 u;
            u.x = pk2(f.x, f.y); u.y = pk2(f.z, f.w);
            *(uint2*)(PW + e) = u;
        } else if (t < NW4 + NP4 + NB4) {
            int e = (t - NW4 - NP4) * 4;
            float4 f = (e < 384) ? *(const float4*)(q_b + e)
                                 : *(const float4*)(kv_b + e - 384);
            *(float4*)(ballf + e) = f;
        }
    } else {
        int h = bx - 1346;
        for (int i = tid; i < 3969; i += 256)
            tabT[h * TS_ + i] = tab[(size_t)(3968 - i) * NH_ + h] * C2_;
        if (tid < 3) tabT[h * TS_ + 3969 + tid] = 0.0f;
    }
}

// ---------------------------------------------------------------------------
// qkv_gemm10: qkv_gemm9 + depth-2 prefetch (3 LDS buffers, two tiles in
// flight). Steady-state wait vmcnt(6) = the 6 ops of tiles t+1,t+2; tile t's
// 3 ops (oldest) are retired by in-order vmcnt semantics. Same addressing.
// LDS 36 KB.
// ---------------------------------------------------------------------------
__global__ __launch_bounds__(256) void qkv_gemm10(
    const ushort* __restrict__ xT, const ushort* __restrict__ Wall,
    const float* __restrict__ ballf, ushort* __restrict__ Qt,
    ushort* __restrict__ Kt, ushort* __restrict__ Vtc)
{
    const int b = blockIdx.z, n0 = blockIdx.x * 128, d0 = blockIdx.y * 64;
    __shared__ ushort As[3][128 * 32];   // 24 KB
    __shared__ ushort Bs[3][64 * 32];    // 12 KB
    const int tid = threadIdx.x;
    const int lane = tid & 63, wave = tid >> 6;
    const int quad = lane >> 4, l16 = lane & 15;
    const int wn = (wave & 1) * 64, wd = (wave >> 1) * 32;

    f32x4 acc[4][2] = {};                // [n][d]
    const ushort* xb = xT + ((size_t)b * N_ + n0) * C_;
    const ushort* wb2 = Wall + (size_t)d0 * C_;
    const int rowA = wave * 16 + (lane >> 2);
    const int fstage = ((lane >> 2) ^ (lane >> 4)) & 3;           // staging swizzle
    const int coff = ((lane & 3) ^ fstage) * 8;
    const int fread = ((l16 & 3) ^ ((l16 >> 2) & 3));             // read swizzle
    const bool isV = (d0 >= 768);
    const int lo = wave * 512;           // ushort offset of this wave's 1KB chunk

    // prologue: stage tiles 0 and 1 (6 vmem ops/wave outstanding)
    #pragma unroll
    for (int t0 = 0; t0 < 2; ++t0) {
        int c0 = t0 * 32;
        #pragma unroll
        for (int k = 0; k < 2; ++k)
            gl2lds16(xb + (size_t)(k * 64 + rowA) * C_ + c0 + coff,
                     &As[t0][k * 2048 + lo]);
        gl2lds16(wb2 + (size_t)rowA * C_ + c0 + coff, &Bs[t0][lo]);
    }

    int cur = 0, nxt = 2;
    for (int it = 0; it < 12; ++it) {
        if (it < 10) {
            int c0 = (it + 2) * 32;
            #pragma unroll
            for (int k = 0; k < 2; ++k)
                gl2lds16(xb + (size_t)(k * 64 + rowA) * C_ + c0 + coff,
                         &As[nxt][k * 2048 + lo]);
            gl2lds16(wb2 + (size_t)rowA * C_ + c0 + coff, &Bs[nxt][lo]);
            asm volatile("s_waitcnt vmcnt(6)" ::: "memory");   // tile t landed
        } else if (it == 10) {
            asm volatile("s_waitcnt vmcnt(3)" ::: "memory");   // tile 10 landed
        } else {
            asm volatile("s_waitcnt vmcnt(0)" ::: "memory");   // tile 11 landed
        }
        __builtin_amdgcn_sched_barrier(0);
        __builtin_amdgcn_s_barrier();        // all waves' tile-t loads landed

        bf16x8 af[4], bfr[2];
        #pragma unroll
        for (int i = 0; i < 4; ++i)
            af[i] = *(const bf16x8*)&As[cur][(wn + i * 16 + l16) * 32 + (quad ^ fread) * 8];
        #pragma unroll
        for (int j = 0; j < 2; ++j)
            bfr[j] = *(const bf16x8*)&Bs[cur][(wd + j * 16 + l16) * 32 + (quad ^ fread) * 8];
        if (!isV) {
            #pragma unroll
            for (int i = 0; i < 2; ++i)
                #pragma unroll
                for (int j = 0; j < 4; ++j)
                    acc[j][i] = __builtin_amdgcn_mfma_f32_16x16x32_bf16(bfr[i], af[j], acc[j][i], 0, 0, 0);
        } else {
            #pragma unroll
            for (int i = 0; i < 4; ++i)
                #pragma unroll
                for (int j = 0; j < 2; ++j)
                    acc[i][j] = __builtin_amdgcn_mfma_f32_16x16x32_bf16(af[i], bfr[j], acc[i][j], 0, 0, 0);
        }
        __builtin_amdgcn_s_barrier();        // buf[cur] reads done before overwrite (staged next iter)
        cur = (cur == 2) ? 0 : cur + 1;
        nxt = (nxt == 2) ? 0 : nxt + 1;
    }

    if (!isV) {
        ushort* dst = (d0 < 384) ? Qt : Kt;
        const float sc = (d0 < 384) ? C1_ : 1.0f;
        const int reg0 = (d0 < 384) ? 0 : 384;
        #pragma unroll
        for (int i = 0; i < 2; ++i) {
            int dloc = wd + i * 16;
            int dg = d0 - reg0 + dloc;
            int h = dg >> 5;
            int dc = (dg & 31) + quad * 4;
            float4 bvv = *(const float4*)(ballf + d0 + dloc + quad * 4);
            size_t hb = (size_t)(b * NH_ + h) * N_;
            #pragma unroll
            for (int j = 0; j < 4; ++j) {
                int n = n0 + wn + j * 16 + l16;
                uint2 w;
                w.x = pk2((acc[j][i][0] + bvv.x) * sc, (acc[j][i][1] + bvv.y) * sc);
                w.y = pk2((acc[j][i][2] + bvv.z) * sc, (acc[j][i][3] + bvv.w) * sc);
                *(uint2*)(dst + (hb + n) * 32 + dc) = w;
            }
        }
    } else {
        #pragma unroll
        for (int j = 0; j < 2; ++j) {
            int dloc = wd + j * 16 + l16;
            int vd = d0 - 768 + dloc;
            int h = vd >> 5, dc = vd & 31;
            float bv = ballf[d0 + dloc];
            size_t hbase = (size_t)(b * NH_ + h) * 32768 + dc * 32;
            #pragma unroll
            for (int i = 0; i < 4; ++i) {
                int n = n0 + wn + i * 16 + quad * 4;
                size_t cbase = hbase + (size_t)((n >> 5)) * 1024 + (n & 31);
                uint2 w;
                w.x = pk2(acc[i][j][0] + bv, acc[i][j][1] + bv);
                w.y = pk2(acc[i][j][2] + bv, acc[i][j][3] + bv);
                *(uint2*)(Vtc + cbase) = w;
            }
        }
    }
}

// ---------------------------------------------------------------------------
// attn11 (r6/r10-verified): reg-dbuf K/V prefetch + strip-split.
// ---------------------------------------------------------------------------
#define LOADKV(K0,K1,K2,K3,V00,V01,V10,V11, MC)                                 \
    { const ushort* kp_ = Kbh + (MC) * 2048;                                    \
      K0 = *(const bf16x8*)(kp_ + ( 0 + l16) * 32 + quad * 8);                  \
      K1 = *(const bf16x8*)(kp_ + (16 + l16) * 32 + quad * 8);                  \
      K2 = *(const bf16x8*)(kp_ + (32 + l16) * 32 + quad * 8);                  \
      K3 = *(const bf16x8*)(kp_ + (48 + l16) * 32 + quad * 8);                  \
      const ushort* vp_ = Vbh + (MC) * 2048;                                    \
      V00 = *(const bf16x8*)(vp_ +        ( 0 + l16) * 32 + quad * 8);          \
      V01 = *(const bf16x8*)(vp_ +        (16 + l16) * 32 + quad * 8);          \
      V10 = *(const bf16x8*)(vp_ + 1024 + ( 0 + l16) * 32 + quad * 8);          \
      V11 = *(const bf16x8*)(vp_ + 1024 + (16 + l16) * 32 + quad * 8); }

#define COMPUTE(MC, K0,K1,K2,K3,V00,V01,V10,V11)                                \
    { const float* Tb = tabL + ibx0 + (MC) * 126 + quad * 4;                    \
      f32x4 tvm16, tv0, tv16, tv47, tv63, tv79;                                 \
      _Pragma("unroll")                                                         \
      for (int e = 0; e < 4; ++e) {                                             \
          tvm16[e] = Tb[e - 16];                                                \
          tv0[e]   = Tb[e];                                                     \
          tv16[e]  = Tb[e + 16];                                                \
          tv47[e]  = Tb[e + 47];                                                \
          tv63[e]  = Tb[e + 63];                                                \
          tv79[e]  = Tb[e + 79];                                                \
      }                                                                         \
      f32x4 cbs[2][4] = {{tv0, tv16, tv63, tv79}, {tvm16, tv0, tv47, tv63}};    \
      _Pragma("unroll")                                                         \
      for (int st = 0; st < 2; ++st) {                                          \
          __builtin_amdgcn_s_setprio(1);                                        \
          f32x4 s0 = __builtin_amdgcn_mfma_f32_16x16x32_bf16(K0, qf[st], cbs[st][0], 0, 0, 0); \
          f32x4 s1 = __builtin_amdgcn_mfma_f32_16x16x32_bf16(K1, qf[st], cbs[st][1], 0, 0, 0); \
          f32x4 s2 = __builtin_amdgcn_mfma_f32_16x16x32_bf16(K2, qf[st], cbs[st][2], 0, 0, 0); \
          f32x4 s3 = __builtin_amdgcn_mfma_f32_16x16x32_bf16(K3, qf[st], cbs[st][3], 0, 0, 0); \
          __builtin_amdgcn_s_setprio(0);                                        \
          ushort* Pw = PwBase + st * 1024;                                      \
          f32x4 sv[4] = {s0, s1, s2, s3};                                       \
          _Pragma("unroll")                                                     \
          for (int t = 0; t < 4; ++t) {                                         \
              float p0 = EXP2(sv[t][0]);                                        \
              float p1 = EXP2(sv[t][1]);                                        \
              float p2 = EXP2(sv[t][2]);                                        \
              float p3 = EXP2(sv[t][3]);                                        \
              uint2 w;                                                          \
              w.x = pk2(p0, p1);                                                \
              w.y = pk2(p2, p3);                                                \
              *(uint2*)(Pw + l16 * 64 + (((t * 4 + quad) ^ pswz) * 4)) = w;     \
          }                                                                     \
      }                                                                         \
      _Pragma("unroll")                                                         \
      for (int st = 0; st < 2; ++st) {                                          \
          ushort* Pw = PwBase + st * 1024;                                      \
          __builtin_amdgcn_s_setprio(1);                                        \
          { bf16x8 pb = *(const bf16x8*)(Pw + l16 * 64 + (((0 + quad * 2) ^ pswz) * 4)); \
            lacc[st]    = __builtin_amdgcn_mfma_f32_16x16x32_bf16(ones, pb, lacc[st], 0, 0, 0); \
            oacc[st][0] = __builtin_amdgcn_mfma_f32_16x16x32_bf16(V00, pb, oacc[st][0], 0, 0, 0); \
            oacc[st][1] = __builtin_amdgcn_mfma_f32_16x16x32_bf16(V01, pb, oacc[st][1], 0, 0, 0); } \
          { bf16x8 pb = *(const bf16x8*)(Pw + l16 * 64 + (((8 + quad * 2) ^ pswz) * 4)); \
            lacc[st]    = __builtin_amdgcn_mfma_f32_16x16x32_bf16(ones, pb, lacc[st], 0, 0, 0); \
            oacc[st][0] = __builtin_amdgcn_mfma_f32_16x16x32_bf16(V10, pb, oacc[st][0], 0, 0, 0); \
            oacc[st][1] = __builtin_amdgcn_mfma_f32_16x16x32_bf16(V11, pb, oacc[st][1], 0, 0, 0); } \
          __builtin_amdgcn_s_setprio(0);                                        \
      } }

__global__ __launch_bounds__(256, 3) void attn11(
    const ushort* __restrict__ Qt, const ushort* __restrict__ Kt,
    const ushort* __restrict__ Vtc, const float* __restrict__ tabT,
    ushort* __restrict__ O)
{
    const int bid = blockIdx.x;      // (b*12+h) + 96*nx
    const int bh96 = bid % 96;
    const int nx = bid / 96;
    const int b = bh96 / 12, h = bh96 % 12;

    __shared__ float tabL[TS_];
    __shared__ ushort Pa[8192];      // 4 waves x 2 strips x 16 x 64

    const int tid = threadIdx.x;
    const int lane = tid & 63, wave = tid >> 6;
    const int quad = lane >> 4, l16 = lane & 15;
    const int bh = b * NH_ + h;

    {
        const float* th = tabT + h * TS_;
        int i = tid * 4;
        #pragma unroll
        for (int k = 0; k < 4; ++k) {
            if (i < TS_) *(float4*)&tabL[i] = *(const float4*)&th[i];
            i += 1024;
        }
    }
    __syncthreads();

    const int qs0 = nx * 8 + wave * 2;
    const ushort* Kbh = Kt + (size_t)bh * N_ * 32;
    const ushort* Vbh = Vtc + (size_t)bh * 16 * 2048;

    bf16x8 qf[2];
    #pragma unroll
    for (int st = 0; st < 2; ++st) {
        int q = (qs0 + st) * 16 + l16;
        qf[st] = *(const bf16x8*)(Qt + ((size_t)bh * N_ + q) * 32 + quad * 8);
    }
    int ibx0;
    {
        int q = qs0 * 16 + l16;
        ibx0 = (31 - (q >> 5)) * 63 + (31 - (q & 31));
    }

    bf16x8 ones;
    #pragma unroll
    for (int j = 0; j < 8; ++j) ones[j] = (__bf16)1.0f;

    f32x4 oacc[2][2] = {};
    f32x4 lacc[2] = {};

    ushort* PwBase = &Pa[wave * 2048];
    const int pswz = l16 & 0xE;

    // register double-buffer: ka*/va* = current, kb*/vb* = next
    bf16x8 ka0, ka1, ka2, ka3, va00, va01, va10, va11;
    bf16x8 kb0, kb1, kb2, kb3, vb00, vb01, vb10, vb11;

    LOADKV(ka0, ka1, ka2, ka3, va00, va01, va10, va11, 0)
    for (int mc = 0; mc < 16; mc += 2) {
        LOADKV(kb0, kb1, kb2, kb3, vb00, vb01, vb10, vb11, mc + 1)
        COMPUTE(mc, ka0, ka1, ka2, ka3, va00, va01, va10, va11)
        if (mc < 14)
            LOADKV(ka0, ka1, ka2, ka3, va00, va01, va10, va11, mc + 2)
        COMPUTE(mc + 1, kb0, kb1, kb2, kb3, vb00, vb01, vb10, vb11)
    }

    #pragma unroll
    for (int st = 0; st < 2; ++st) {
        float inv = 1.0f / lacc[st][0];
        int q = (qs0 + st) * 16 + l16;
        ushort* ob = O + ((size_t)(b * N_ + q)) * C_ + h * HD_;
        #pragma unroll
        for (int dt = 0; dt < 2; ++dt) {
            uint2 w;
            w.x = pk2(oacc[st][dt][0] * inv, oacc[st][dt][1] * inv);
            w.y = pk2(oacc[st][dt][2] * inv, oacc[st][dt][3] * inv);
            *(uint2*)(ob + dt * 16 + quad * 4) = w;
        }
    }
}

// ---------------------------------------------------------------------------
// proj67: proj66 + depth-2 prefetch (3 buffers, vmcnt(4) steady-state).
// ---------------------------------------------------------------------------
__global__ __launch_bounds__(256) void proj67(
    const ushort* __restrict__ O, const ushort* __restrict__ PW,
    const float* __restrict__ pb, float* __restrict__ out)
{
    __shared__ ushort As_[3][2048];   // 12 KB
    __shared__ ushort Bs_[3][2048];   // 12 KB
    const int tid = threadIdx.x;
    const int lane = tid & 63, wave = tid >> 6;
    const int quad = lane >> 4, l16 = lane & 15;
    const int nx = blockIdx.x, dy = blockIdx.y, b = blockIdx.z;
    const int n0 = nx * 64, d0 = dy * 64;
    const int wd = (wave & 1) * 32, wn = (wave >> 1) * 32;

    f32x4 acc[2][2] = {};
    const ushort* ab = PW + (size_t)d0 * C_;
    const ushort* bbp = O + ((size_t)b * N_ + n0) * C_;
    const int rowA = wave * 16 + (lane >> 2);
    const int fstage = ((lane >> 2) ^ (lane >> 4)) & 3;
    const int coff = ((lane & 3) ^ fstage) * 8;
    const int fread = ((l16 & 3) ^ ((l16 >> 2) & 3));
    const int lo = wave * 512;

    #pragma unroll
    for (int t0 = 0; t0 < 2; ++t0) {
        int c0 = t0 * 32;
        gl2lds16(ab + (size_t)rowA * C_ + c0 + coff, &As_[t0][lo]);
        gl2lds16(bbp + (size_t)rowA * C_ + c0 + coff, &Bs_[t0][lo]);
    }

    int cur = 0, nxt = 2;
    for (int it = 0; it < 12; ++it) {
        if (it < 10) {
            int c0 = (it + 2) * 32;
            gl2lds16(ab + (size_t)rowA * C_ + c0 + coff, &As_[nxt][lo]);
            gl2lds16(bbp + (size_t)rowA * C_ + c0 + coff, &Bs_[nxt][lo]);
            asm volatile("s_waitcnt vmcnt(4)" ::: "memory");
        } else if (it == 10) {
            asm volatile("s_waitcnt vmcnt(2)" ::: "memory");
        } else {
            asm volatile("s_waitcnt vmcnt(0)" ::: "memory");
        }
        __builtin_amdgcn_sched_barrier(0);
        __builtin_amdgcn_s_barrier();

        bf16x8 af[2], bfr[2];
        #pragma unroll
        for (int i = 0; i < 2; ++i)
            af[i] = *(const bf16x8*)&As_[cur][(wd + i * 16 + l16) * 32 + (quad ^ fread) * 8];
        #pragma unroll
        for (int j = 0; j < 2; ++j)
            bfr[j] = *(const bf16x8*)&Bs_[cur][(wn + j * 16 + l16) * 32 + (quad ^ fread) * 8];
        #pragma unroll
        for (int i = 0; i < 2; ++i)
            #pragma unroll
            for (int j = 0; j < 2; ++j)
                acc[i][j] = __builtin_amdgcn_mfma_f32_16x16x32_bf16(af[i], bfr[j], acc[i][j], 0, 0, 0);
        __builtin_amdgcn_s_barrier();
        cur = (cur == 2) ? 0 : cur + 1;
        nxt = (nxt == 2) ? 0 : nxt + 1;
    }

    #pragma unroll
    for (int i = 0; i < 2; ++i) {
        #pragma unroll
        for (int r = 0; r < 4; ++r) {
            int d = d0 + wd + i * 16 + quad * 4 + r;
            float bv = pb[d];
            float* op = out + ((size_t)b * C_ + d) * N_ + n0 + wn;
            #pragma unroll
            for (int j = 0; j < 2; ++j)
                op[j * 16 + l16] = acc[i][j][r] + bv;
        }
    }
}

// ---------------------------------------------------------------------------
extern "C" void kernel_launch(void* const* d_in, const int* in_sizes, int n_in,
                              void* d_out, int out_size, void* d_ws, size_t ws_size,
                              hipStream_t stream)
{
    const float* x      = (const float*)d_in[0];
    const float* q_w    = (const float*)d_in[1];
    const float* q_b    = (const float*)d_in[2];
    const float* kv_w   = (const float*)d_in[3];
    const float* kv_b   = (const float*)d_in[4];
    const float* proj_w = (const float*)d_in[5];
    const float* proj_b = (const float*)d_in[6];
    const float* rpb    = (const float*)d_in[7];
    float* out = (float*)d_out;

    char* ws = (char*)d_ws;
    ushort* xT    = (ushort*)(ws);                       //  6,291,456
    ushort* Qt    = (ushort*)(ws +  6291456);            //  6,291,456
    ushort* Kt    = (ushort*)(ws + 12582912);            //  6,291,456
    ushort* Vtc   = (ushort*)(ws + 18874368);            //  6,291,456
    ushort* O     = (ushort*)(ws + 25165824);            //  6,291,456
    float*  tabT  = (float*) (ws + 31457280);            //    190,656 (12 x 3972 x 4)
    ushort* Wall  = (ushort*)(ws + 31647936);            //    884,736
    ushort* PW    = (ushort*)(ws + 32532672);            //    294,912
    float*  ballf = (float*) (ws + 32827584);            //      4,608

    setup      <<<dim3(1358), 256, 0, stream>>>(x, q_w, kv_w, proj_w, q_b, kv_b, rpb,
                                                xT, tabT, Wall, PW, ballf);
    qkv_gemm10 <<<dim3(8, 18, B_), 256, 0, stream>>>(xT, Wall, ballf, Qt, Kt, Vtc);
    attn11     <<<dim3(768), 256, 0, stream>>>(Qt, Kt, Vtc, tabT, O);
    proj67     <<<dim3(16, 6, B_), 256, 0, stream>>>(O, PW, proj_b, out);
}